// Round 6
// baseline (53623.328 us; speedup 1.0000x reference)
//
#include <hip/hip_runtime.h>
#include <cstdio>

// HardLSTM (2 layers, T=512, B=32, IN=H=1024) on MI355X.
// Round 6: MEASUREMENT ROUND. rec_fused is byte-identical to round 5 (control).
// Four probe kernels run first; their per-dispatch durations in rocprof
// decompose the stubborn ~16.5 us/step:
//   probe_bar_global x2048 : exact r5 barrier (store+vmcnt+flag+spin128, LLC)
//   probe_bar_xcd    x8192 : same barrier among 32 blocks of one physical XCD,
//                            flags via plain-store + sc0-load (local L2 path)
//   probe_pair       x2048 : 2-block cross-die flag ping-pong (LLC atomics)
//   probe_data       x2048 : 64KB broadcast ldA stream (h-half data path)
// All probes have a 25ms realtime budget (cannot hang); results read from
// their dispatch durations only. Probe state lives in ws and is memset per
// launch; outputs are untouched by probes.

#define T_STEPS 512
#define BATCH   32
#define HID     1024
#define PROBE_BUDGET 2500000ULL   // 25 ms @ 100 MHz s_memrealtime

typedef __bf16 bf16x8 __attribute__((ext_vector_type(8)));
typedef float  f32x4  __attribute__((ext_vector_type(4)));
typedef unsigned int u32x4 __attribute__((ext_vector_type(4)));
typedef unsigned long long u64;

#define AGLD(p)    __hip_atomic_load((p), __ATOMIC_RELAXED, __HIP_MEMORY_SCOPE_AGENT)
#define AGST(p,v)  __hip_atomic_store((p), (v), __ATOMIC_RELAXED, __HIP_MEMORY_SCOPE_AGENT)

__device__ __forceinline__ unsigned short f2bf(float f){
  union { float f; unsigned u; } v; v.f = f;
  unsigned r = v.u + 0x7FFFu + ((v.u >> 16) & 1u);   // RNE
  return (unsigned short)(r >> 16);
}

__device__ __forceinline__ bf16x8 ldg_frag(const unsigned short* p){
  u32x4 v = *reinterpret_cast<const u32x4*>(p);
  return __builtin_bit_cast(bf16x8, v);
}
__device__ __forceinline__ bf16x8 ldA(const unsigned short* p){
  const u64* q = reinterpret_cast<const u64*>(p);
  u64 v0 = AGLD(q);
  u64 v1 = AGLD(q + 1);
  union { u64 u[2]; bf16x8 f; } w; w.u[0] = v0; w.u[1] = v1; return w.f;
}
__device__ __forceinline__ bf16x8 lds_frag(const unsigned short* ldsW, int fi, int lane){
  u32x4 v = *reinterpret_cast<const u32x4*>(ldsW + fi*512 + lane*8);
  return __builtin_bit_cast(bf16x8, v);
}

// r5 spin: 128 flags packed 2 per 128B line; lane i polls line i via one u64.
__device__ __forceinline__ void spin_flags(const unsigned int* f, unsigned target, int lane){
  const u64* p = reinterpret_cast<const u64*>(f) + (size_t)lane*16;   // 128B stride
  while (true){
    u64 v = AGLD(p);
    unsigned a = (unsigned)v, b = (unsigned)(v >> 32);
    if (__all((int)(a >= target && b >= target))) break;
  }
  asm volatile("" ::: "memory");
}

#define MFMA16 __builtin_amdgcn_mfma_f32_16x16x32_bf16

// ---------------- prep kernels ----------------

__global__ void prep_x(const float* __restrict__ x, unsigned short* __restrict__ xbf, int n8){
  int idx = blockIdx.x*blockDim.x + threadIdx.x;
  int stride = gridDim.x*blockDim.x;
  for (int i = idx; i < n8; i += stride){
    const f32x4* p = reinterpret_cast<const f32x4*>(x + (size_t)i*8);
    f32x4 v0 = p[0], v1 = p[1];
    unsigned u0 = f2bf(v0[0]+1.f) | ((unsigned)f2bf(v0[1]+1.f)<<16);
    unsigned u1 = f2bf(v0[2]+1.f) | ((unsigned)f2bf(v0[3]+1.f)<<16);
    unsigned u2 = f2bf(v1[0]+1.f) | ((unsigned)f2bf(v1[1]+1.f)<<16);
    unsigned u3 = f2bf(v1[2]+1.f) | ((unsigned)f2bf(v1[3]+1.f)<<16);
    u32x4 cv = {u0,u1,u2,u3};
    *reinterpret_cast<u32x4*>(xbf + (size_t)i*8) = cv;
  }
}

__global__ void reduce_mean_f32(const float* __restrict__ src, float* __restrict__ out, float add){
  __shared__ float red[256];
  int t = blockIdx.x, tid = threadIdx.x;
  const float* p = src + (size_t)t*32768;
  float s = 0.f;
  for (int i = tid; i < 32768; i += 256) s += p[i];
  red[tid] = s; __syncthreads();
  for (int o = 128; o > 0; o >>= 1){ if (tid < o) red[tid] += red[tid+o]; __syncthreads(); }
  if (tid == 0) out[t] = red[0]*(1.f/32768.f) + add;
}

__global__ void prep_rs(const float* __restrict__ Wih0, const float* __restrict__ Whh0,
                        const float* __restrict__ Wih1, const float* __restrict__ Whh1,
                        const float* __restrict__ bih0, const float* __restrict__ bhh0,
                        const float* __restrict__ bih1, const float* __restrict__ bhh1,
                        float* __restrict__ rs, float* __restrict__ bias){
  int task = blockIdx.x*4 + (threadIdx.x >> 6);
  int lane = threadIdx.x & 63;
  int L = task >> 12, n = task & 4095;
  const float* pi = (L ? Wih1 : Wih0) + (size_t)n*1024;
  const float* ph = (L ? Whh1 : Whh0) + (size_t)n*1024;
  float s = 0.f;
  #pragma unroll
  for (int e = 0; e < 16; ++e){ int k = lane + e*64; s += pi[k] + ph[k]; }
  #pragma unroll
  for (int m = 32; m; m >>= 1) s += __shfl_xor(s, m);
  if (lane == 0){
    rs[task]   = s;
    bias[task] = (L ? bih1[n] : bih0[n]) + (L ? bhh1[n] : bhh0[n]);
  }
}

__global__ void prep_hinit(const float* __restrict__ h0, unsigned short* __restrict__ hini){
  int i = blockIdx.x*256 + threadIdx.x;
  hini[i] = f2bf(h0[i]);
}

// ---------------- probes ----------------

// P1: exact r5-style global barrier over 2 groups of 128 blocks (LLC atomics).
__global__ __launch_bounds__(64) void probe_bar_global(unsigned int* flags, unsigned int* sink, int niter){
  __shared__ unsigned short lds[65536];
  int lane = threadIdx.x;
  int g = blockIdx.x >> 7, bid = blockIdx.x & 127;
  lds[lane] = (unsigned short)bid;
  unsigned int* base = flags + (size_t)g*128*32;        // 128 lines x 128B
  unsigned int* my   = base + (size_t)bid*32;
  const unsigned int* p0 = base + (size_t)lane*32;
  const unsigned int* p1 = base + (size_t)(lane+64)*32;
  u64 t0 = __builtin_amdgcn_s_memrealtime();
  bool timeout = false;
  for (int k = 1; k <= niter && !timeout; ++k){
    AGST(my + 4, (unsigned)k);                          // payload store (same line)
    asm volatile("s_waitcnt vmcnt(0)" ::: "memory");
    AGST(my, (unsigned)k);
    while (true){
      unsigned a = AGLD(p0), b = AGLD(p1);
      if (__all((int)(a >= (unsigned)k && b >= (unsigned)k))) break;
      if (__builtin_amdgcn_s_memrealtime() - t0 > PROBE_BUDGET){ timeout = true; break; }
    }
  }
  if (lane == 0) sink[blockIdx.x] = timeout ? 2u : 1u;
}

// P2: barrier among the 32 blocks of ONE physical XCD, flags via plain store +
// sc0 load (local-L2 coherence path). Election via per-XCD LLC counter.
__global__ __launch_bounds__(64) void probe_bar_xcd(unsigned int* flagsX, unsigned int* elect,
                                                    unsigned int* sink, int niter){
  __shared__ unsigned short lds[65536];
  int lane = threadIdx.x;
  lds[lane] = 1;
  unsigned xcc;
  asm volatile("s_getreg_b32 %0, hwreg(HW_REG_XCC_ID)" : "=s"(xcc));
  xcc &= 7;
  unsigned rank = 0;
  if (lane == 0)
    rank = __hip_atomic_fetch_add(elect + xcc*32, 1u, __ATOMIC_RELAXED, __HIP_MEMORY_SCOPE_AGENT);
  rank = (unsigned)__shfl((int)rank, 0);
  unsigned int* base = flagsX + (size_t)xcc*32*32;      // 32 lines x 128B per XCD
  u64 myA  = (u64)(uintptr_t)(base + (size_t)(rank & 31)*32);
  u64 pollA= (u64)(uintptr_t)(base + (size_t)(lane & 31)*32);
  u64 t0 = __builtin_amdgcn_s_memrealtime();
  bool timeout = false;
  for (int k = 1; k <= niter && !timeout; ++k){
    asm volatile("global_store_dword %0, %1, off\n\ts_waitcnt vmcnt(0)"
                 :: "v"(myA), "v"((unsigned)k) : "memory");
    while (true){
      unsigned v;
      asm volatile("global_load_dword %0, %1, off sc0\n\ts_waitcnt vmcnt(0)"
                   : "=v"(v) : "v"(pollA) : "memory");
      if (__all((int)(v >= (unsigned)k))) break;
      if (__builtin_amdgcn_s_memrealtime() - t0 > PROBE_BUDGET){ timeout = true; break; }
    }
  }
  if (lane == 0) sink[256 + blockIdx.x] = timeout ? 2u : 1u;
}

// P3: 2-block cross-die ping-pong via LLC atomics. Others exit immediately.
__global__ __launch_bounds__(64) void probe_pair(unsigned int* f, unsigned int* sink, int niter){
  __shared__ unsigned short lds[65536];
  int lane = threadIdx.x;
  lds[lane] = 2;
  u64 t0 = __builtin_amdgcn_s_memrealtime();
  bool timeout = false;
  if (blockIdx.x == 0){
    for (int k = 1; k <= niter && !timeout; ++k){
      AGST(f, (unsigned)k);
      while (AGLD(f + 32) < (unsigned)k){
        if (__builtin_amdgcn_s_memrealtime() - t0 > PROBE_BUDGET){ timeout = true; break; }
      }
    }
    if (lane == 0) sink[768] = timeout ? 2u : 1u;
  } else if (blockIdx.x == 255){
    for (int k = 1; k <= niter && !timeout; ++k){
      while (AGLD(f) < (unsigned)k){
        if (__builtin_amdgcn_s_memrealtime() - t0 > PROBE_BUDGET){ timeout = true; break; }
      }
      AGST(f + 32, (unsigned)k);
    }
    if (lane == 0) sink[769] = timeout ? 2u : 1u;
  }
}

// P4: 64KB broadcast ldA stream per iter (exact h-half addressing), no sync.
__global__ __launch_bounds__(64) void probe_data(const unsigned short* Xbf,
                                                 unsigned int* sink, int niter){
  __shared__ unsigned short lds[65536];
  int lane = threadIdx.x;
  lds[lane] = 3;
  int l15 = lane & 15, koff = (lane >> 4) << 3;
  u64 acc = 0;
  for (int k = 0; k < niter; ++k){
    const unsigned short* A = Xbf + (size_t)(k & 511)*32768 + l15*HID + koff;
    #pragma unroll 4
    for (int kt = 0; kt < 32; ++kt){
      const u64* q0 = reinterpret_cast<const u64*>(A + kt*32);
      const u64* q1 = reinterpret_cast<const u64*>(A + 16*HID + kt*32);
      acc ^= AGLD(q0); acc ^= AGLD(q0 + 1);
      acc ^= AGLD(q1); acc ^= AGLD(q1 + 1);
    }
  }
  if (lane == 0) sink[512 + blockIdx.x] = (unsigned)acc ^ (unsigned)(acc >> 32);
}

// ---------------- fused persistent recurrent kernel (r5, unchanged) ----------------
__global__ __launch_bounds__(64) void rec_fused(
    const unsigned short* __restrict__ Xbf,
    const unsigned short* __restrict__ Hini,
    unsigned short* __restrict__ Ring0,
    unsigned short* __restrict__ Ring1,
    float* __restrict__ out,
    const float* __restrict__ Wih0, const float* __restrict__ Whh0,
    const float* __restrict__ Wih1, const float* __restrict__ Whh1,
    const float* __restrict__ biasC, const float* __restrict__ rsC,
    const float* __restrict__ eps0,
    const float* __restrict__ c0,
    unsigned int* __restrict__ flag0,
    unsigned int* __restrict__ flag1,
    int* __restrict__ epsP)
{
  __shared__ unsigned short ldsW[65536];
  const int lane = threadIdx.x;
  const int L    = blockIdx.x >> 7;
  const int bid  = blockIdx.x & 127;
  const int jb   = bid * 8;
  const int l15  = lane & 15;
  const int koff = (lane >> 4) << 3;
  const bool isLow = (l15 < 8);

  const float* Wih = L ? Wih1 : Wih0;
  const float* Whh = L ? Whh1 : Whh0;

  for (int fi = 0; fi < 128; ++fi){
    int ktg = fi >> 1, nt = fi & 1;
    int r = nt*16 + l15;
    int n = (r >> 3)*1024 + jb + (r & 7);
    int k0 = ktg*32 + koff;
    const float* src = (k0 < 1024) ? (Wih + (size_t)n*1024 + k0)
                                   : (Whh + (size_t)n*1024 + (k0 - 1024));
    f32x4 w0 = *reinterpret_cast<const f32x4*>(src);
    f32x4 w1 = *reinterpret_cast<const f32x4*>(src + 4);
    unsigned u0 = f2bf(w0[0]) | ((unsigned)f2bf(w0[1])<<16);
    unsigned u1 = f2bf(w0[2]) | ((unsigned)f2bf(w0[3])<<16);
    unsigned u2 = f2bf(w1[0]) | ((unsigned)f2bf(w1[1])<<16);
    unsigned u3 = f2bf(w1[2]) | ((unsigned)f2bf(w1[3])<<16);
    u32x4 cv = {u0,u1,u2,u3};
    *reinterpret_cast<u32x4*>(&ldsW[fi*512 + lane*8]) = cv;
  }

  int c0s = l15, c1s = 16 + l15;
  int n0 = L*4096 + (c0s >> 3)*1024 + jb + (c0s & 7);
  int n1 = L*4096 + (c1s >> 3)*1024 + jb + (c1s & 7);
  float bia0 = biasC[n0], rsv0 = rsC[n0];
  float bia1 = biasC[n1], rsv1 = rsC[n1];

  const int bq = (lane >> 4) * 4;
  const int jw = jb + (lane & 7);
  float creg[2][4];
  #pragma unroll
  for (int m = 0; m < 2; ++m)
    #pragma unroll
    for (int r = 0; r < 4; ++r)
      creg[m][r] = c0[L*32768 + (m*16 + bq + r)*1024 + jw];

  float* outHn = out + 16777216 + L*32768;
  float* outCn = out + 16777216 + 65536 + L*32768;
  unsigned int* myflag = (L ? flag1 : flag0) + (size_t)(bid >> 1)*32 + (bid & 1);

  for (int t = 0; t < T_STEPS; ++t){
    f32x4 acc00 = {0.f,0.f,0.f,0.f}, acc01 = {0.f,0.f,0.f,0.f};
    f32x4 acc10 = {0.f,0.f,0.f,0.f}, acc11 = {0.f,0.f,0.f,0.f};
    float et;

    if (L == 0){
      const unsigned short* A0 = Xbf + (size_t)t*32768 + l15*HID + koff;
      #pragma unroll 4
      for (int kt = 0; kt < 32; ++kt){
        bf16x8 a0 = ldg_frag(A0 + kt*32);
        bf16x8 a1 = ldg_frag(A0 + 16*HID + kt*32);
        bf16x8 b0 = lds_frag(ldsW, kt*2 + 0, lane);
        bf16x8 b1 = lds_frag(ldsW, kt*2 + 1, lane);
        acc00 = MFMA16(a0, b0, acc00, 0, 0, 0);
        acc01 = MFMA16(a0, b1, acc01, 0, 0, 0);
        acc10 = MFMA16(a1, b0, acc10, 0, 0, 0);
        acc11 = MFMA16(a1, b1, acc11, 0, 0, 0);
      }
      et = eps0[t];
      if (t > 0) spin_flags(flag0, (unsigned)t, lane);
      const unsigned short* Ah = ((t == 0) ? Hini : Ring0 + (size_t)(t-1)*32768)
                                 + l15*HID + koff;
      #pragma unroll 4
      for (int kt = 0; kt < 32; ++kt){
        bf16x8 a0 = ldA(Ah + kt*32);
        bf16x8 a1 = ldA(Ah + 16*HID + kt*32);
        bf16x8 b0 = lds_frag(ldsW, (32+kt)*2 + 0, lane);
        bf16x8 b1 = lds_frag(ldsW, (32+kt)*2 + 1, lane);
        acc00 = MFMA16(a0, b0, acc00, 0, 0, 0);
        acc01 = MFMA16(a0, b1, acc01, 0, 0, 0);
        acc10 = MFMA16(a1, b0, acc10, 0, 0, 0);
        acc11 = MFMA16(a1, b1, acc11, 0, 0, 0);
      }
    } else {
      if (t > 0) spin_flags(flag1, (unsigned)t, lane);
      const unsigned short* Ah = ((t == 0) ? Hini + 32768 : Ring1 + (size_t)((t-1)&7)*32768)
                                 + l15*HID + koff;
      #pragma unroll 4
      for (int kt = 0; kt < 32; ++kt){
        bf16x8 a0 = ldA(Ah + kt*32);
        bf16x8 a1 = ldA(Ah + 16*HID + kt*32);
        bf16x8 b0 = lds_frag(ldsW, (32+kt)*2 + 0, lane);
        bf16x8 b1 = lds_frag(ldsW, (32+kt)*2 + 1, lane);
        acc00 = MFMA16(a0, b0, acc00, 0, 0, 0);
        acc01 = MFMA16(a0, b1, acc01, 0, 0, 0);
        acc10 = MFMA16(a1, b0, acc10, 0, 0, 0);
        acc11 = MFMA16(a1, b1, acc11, 0, 0, 0);
      }
      spin_flags(flag0, (unsigned)(t+1), lane);
      {
        const u64* ep = reinterpret_cast<const u64*>(epsP + (size_t)t*128);
        u64 v = AGLD(ep + lane);
        int s = (int)(unsigned)v + (int)(unsigned)(v >> 32);
        #pragma unroll
        for (int mm = 32; mm; mm >>= 1) s += __shfl_xor(s, mm);
        et = (float)s * 4.6566128730773926e-10f;
      }
      const unsigned short* Ay = Ring0 + (size_t)t*32768 + l15*HID + koff;
      #pragma unroll 4
      for (int kt = 0; kt < 32; ++kt){
        bf16x8 a0 = ldA(Ay + kt*32);
        bf16x8 a1 = ldA(Ay + 16*HID + kt*32);
        bf16x8 b0 = lds_frag(ldsW, kt*2 + 0, lane);
        bf16x8 b1 = lds_frag(ldsW, kt*2 + 1, lane);
        acc00 = MFMA16(a0, b0, acc00, 0, 0, 0);
        acc01 = MFMA16(a0, b1, acc01, 0, 0, 0);
        acc10 = MFMA16(a1, b0, acc10, 0, 0, 0);
        acc11 = MFMA16(a1, b1, acc11, 0, 0, 0);
      }
    }

    unsigned short* ring = L ? (Ring1 + (size_t)(t & 7)*32768) : (Ring0 + (size_t)t*32768);
    float hyv[2][4], ccv[2][4];
    float psum = 0.f;
    #pragma unroll
    for (int m = 0; m < 2; ++m){
      f32x4 ga = m ? acc10 : acc00;
      f32x4 gb = m ? acc11 : acc01;
      #pragma unroll
      for (int r = 0; r < 4; ++r){
        float g0 = ga[r] + bia0 + et*rsv0;
        float g1 = gb[r] + bia1 + et*rsv1;
        float p0 = __shfl_xor(g0, 8);
        float p1 = __shfl_xor(g1, 8);
        float iv = isLow ? g0 : p0;
        float fv = isLow ? p0 : g0;
        float gv = isLow ? g1 : p1;
        float ov = isLow ? p1 : g1;
        iv = fminf(fmaxf(0.2f*iv + 0.5f, 0.f), 1.f);
        fv = fminf(fmaxf(0.2f*fv + 0.5f, 0.f), 1.f);
        gv = fminf(fmaxf(gv, -1.f), 1.f);
        ov = fminf(fmaxf(0.2f*ov + 0.5f, 0.f), 1.f);
        float cc = fv*(creg[m][r] + et) + iv*gv;
        creg[m][r] = cc;
        float hy = ov * fminf(fmaxf(cc, -1.f), 1.f);
        hyv[m][r] = hy; ccv[m][r] = cc;

        unsigned short hu = f2bf(hy);
        unsigned p2 = (unsigned)hu | (((unsigned)__shfl_xor((int)hu, 1)) << 16);
        unsigned q2 = (unsigned)__shfl_xor((int)p2, 2);
        if (isLow){
          if (!(lane & 3)){
            int b = m*16 + bq + r;
            u64 w = (u64)p2 | ((u64)q2 << 32);
            AGST(reinterpret_cast<u64*>(ring + b*HID + jw), w);
          }
          if (L == 0) psum += hy;
        }
      }
    }
    if (L == 0){
      #pragma unroll
      for (int mm = 32; mm; mm >>= 1) psum += __shfl_xor(psum, mm);
      if (lane == 0)
        AGST(reinterpret_cast<unsigned*>(epsP + (size_t)t*128 + bid),
             (unsigned)(int)llrintf(psum * 65536.f));
    }

    asm volatile("s_waitcnt vmcnt(0)" ::: "memory");
    if (lane == 0) AGST(myflag, (unsigned)(t+1));

    if (L){
      #pragma unroll
      for (int m = 0; m < 2; ++m)
        #pragma unroll
        for (int r = 0; r < 4; ++r){
          float hy = hyv[m][r];
          float f1 = __shfl_xor(hy, 1);
          float f2 = __shfl_xor(hy, 2);
          float f3 = __shfl_xor(f1, 2);
          if (isLow && !(lane & 3)){
            int b = m*16 + bq + r;
            f32x4 o4 = {hy, f1, f2, f3};
            *reinterpret_cast<f32x4*>(out + (size_t)t*32768 + b*HID + jw) = o4;
          }
        }
    }
    if (t == T_STEPS-1){
      #pragma unroll
      for (int m = 0; m < 2; ++m)
        #pragma unroll
        for (int r = 0; r < 4; ++r)
          if (isLow){
            int b = m*16 + bq + r;
            outHn[b*HID + jw] = hyv[m][r];
            outCn[b*HID + jw] = ccv[m][r];
          }
    }
  }
}

// ---------------- host ----------------

extern "C" void kernel_launch(void* const* d_in, const int* in_sizes, int n_in,
                              void* d_out, int out_size, void* d_ws, size_t ws_size,
                              hipStream_t stream)
{
  const float* x    = (const float*)d_in[0];
  const float* h0   = (const float*)d_in[1];
  const float* c0   = (const float*)d_in[2];
  const float* Wih0 = (const float*)d_in[3];
  const float* Whh0 = (const float*)d_in[4];
  const float* bih0 = (const float*)d_in[5];
  const float* bhh0 = (const float*)d_in[6];
  const float* Wih1 = (const float*)d_in[7];
  const float* Whh1 = (const float*)d_in[8];
  const float* bih1 = (const float*)d_in[9];
  const float* bhh1 = (const float*)d_in[10];
  float* out = (float*)d_out;

  char* ws = (char*)d_ws;
  size_t off = 0;
  auto alloc = [&](size_t bytes)->char* {
    char* p = ws + off; off += (bytes + 255) & ~(size_t)255; return p;
  };
  unsigned short* Xbf   = (unsigned short*)alloc((size_t)T_STEPS*BATCH*HID*2); // 32MB
  unsigned short* Ring0 = (unsigned short*)alloc((size_t)T_STEPS*BATCH*HID*2); // 32MB
  unsigned short* Ring1 = (unsigned short*)alloc((size_t)8*BATCH*HID*2);
  unsigned short* Hini  = (unsigned short*)alloc((size_t)2*BATCH*HID*2);
  float* eps0 = (float*)alloc(T_STEPS*4);
  float* bias = (float*)alloc(2*4096*4);
  float* rs   = (float*)alloc(2*4096*4);
  int*   epsP = (int*)alloc((size_t)T_STEPS*128*4);
  // per-launch-zeroed sync area: probe flags + rec flags
  //  [0,32768)      probe_bar_global: 2 groups x 128 lines x 128B
  //  [32768,65536)  probe_bar_xcd: 8 XCDs x 32 lines x 128B
  //  [65536,66560)  elect counters: 8 x 128B
  //  [66560,66816)  probe_pair: 2 lines
  //  [66816,75008)  rec flag0 (64 lines)
  //  [75008,83200)  rec flag1 (64 lines)
  size_t SYNCBYTES = 83200;
  char* sync = alloc(SYNCBYTES);
  unsigned int* barG   = (unsigned int*)sync;
  unsigned int* barX   = (unsigned int*)(sync + 32768);
  unsigned int* elect8 = (unsigned int*)(sync + 65536);
  unsigned int* pairF  = (unsigned int*)(sync + 66560);
  unsigned int* flag0  = (unsigned int*)(sync + 66816);
  unsigned int* flag1  = (unsigned int*)(sync + 75008);
  unsigned int* sink   = (unsigned int*)alloc(4096);
  if (off > ws_size)
    fprintf(stderr, "HardLSTM: ws too small, need %zu have %zu\n", off, ws_size);

  hipMemsetAsync(sync, 0, SYNCBYTES, stream);
  prep_x<<<4096, 256, 0, stream>>>(x, Xbf, (T_STEPS*BATCH*HID)/8);
  reduce_mean_f32<<<T_STEPS, 256, 0, stream>>>(x, eps0, 1.0f);
  prep_rs<<<2048, 256, 0, stream>>>(Wih0, Whh0, Wih1, Whh1, bih0, bhh0, bih1, bhh1, rs, bias);
  prep_hinit<<<256, 256, 0, stream>>>(h0, Hini);

  // ---- probes (sequential, budget-capped, outputs untouched) ----
  probe_bar_global<<<256, 64, 0, stream>>>(barG, sink, 2048);
  probe_bar_xcd  <<<256, 64, 0, stream>>>(barX, elect8, sink, 8192);
  probe_pair     <<<256, 64, 0, stream>>>(pairF, sink, 2048);
  probe_data     <<<256, 64, 0, stream>>>(Xbf, sink, 2048);

  // ---- real computation (r5 control) ----
  rec_fused<<<256, 64, 0, stream>>>(Xbf, Hini, Ring0, Ring1, out,
      Wih0, Whh0, Wih1, Whh1, bias, rs, eps0, c0, flag0, flag1, epsP);
}

// Round 8
// 6417.307 us; speedup vs baseline: 8.3560x; 8.3560x over previous
//
#include <hip/hip_runtime.h>
#include <cstdio>

// HardLSTM (2 layers, T=512, B=32, IN=H=1024) on MI355X.
// Round 8: r5-bit-exact arithmetic (single per-element MFMA chain, x->h for L0,
// h->y0 for L1, same kt order, same bf16 inputs) with a rebuilt transport:
//  - 256-thr blocks (4 waves, 1/SIMD): W second-half in 128 VGPRs, first-half
//    in LDS (64KB); A-tile staged to LDS (64KB) via 16B sc0+sc1 system loads.
//  - packed u16 flags (128 flags = 256B), polled by wave 0 only (16 lanes x
//    one dwordx4) -> ~60x less LLC poll traffic.
//  - full-size Ring0 (no reuse -> no throttle spins).
// All spins deadline-capped (no hang possible).

#define T_STEPS 512
#define DEADLINE_TICKS 6000000ULL   // ~60ms @ 100MHz

typedef __bf16 bf16x8 __attribute__((ext_vector_type(8)));
typedef float  f32x4  __attribute__((ext_vector_type(4)));
typedef unsigned int u32x4 __attribute__((ext_vector_type(4)));
typedef unsigned long long u64;

#define AGLD(p)   __hip_atomic_load((p), __ATOMIC_RELAXED, __HIP_MEMORY_SCOPE_AGENT)
#define AGST(p,v) __hip_atomic_store((p), (v), __ATOMIC_RELAXED, __HIP_MEMORY_SCOPE_AGENT)
#define MFMA16 __builtin_amdgcn_mfma_f32_16x16x32_bf16

__device__ __forceinline__ u64 rtick(){ return __builtin_amdgcn_s_memrealtime(); }

__device__ __forceinline__ unsigned short f2bf(float f){
  union { float f; unsigned u; } v; v.f = f;
  unsigned r = v.u + 0x7FFFu + ((v.u >> 16) & 1u);   // RNE
  return (unsigned short)(r >> 16);
}
__device__ __forceinline__ bf16x8 packbf(f32x4 a, f32x4 b){
  unsigned u0 = f2bf(a[0]) | ((unsigned)f2bf(a[1])<<16);
  unsigned u1 = f2bf(a[2]) | ((unsigned)f2bf(a[3])<<16);
  unsigned u2 = f2bf(b[0]) | ((unsigned)f2bf(b[1])<<16);
  unsigned u3 = f2bf(b[2]) | ((unsigned)f2bf(b[3])<<16);
  u32x4 cv = {u0,u1,u2,u3};
  return __builtin_bit_cast(bf16x8, cv);
}
// frag-layout byte offset of (row 0..31, k8 = k>>3 in 0..127) in a 64KB A-block
__device__ __forceinline__ int fragOff(int row, int k8){
  return ((k8>>2)*2 + (row>>4))*1024 + ((row&15) | ((k8&3)<<4))*16;
}
__device__ __forceinline__ bf16x8 ld_frag_plain(const char* p){
  u32x4 v = *reinterpret_cast<const u32x4*>(p);
  return __builtin_bit_cast(bf16x8, v);
}
__device__ __forceinline__ bf16x8 lds_frag(const char* p){
  u32x4 v = *reinterpret_cast<const u32x4*>(p);
  return __builtin_bit_cast(bf16x8, v);
}

// Stage 64KB global -> LDS with 16B system-scope (sc0 sc1) loads.
// 256 threads x 16 loads x 16B. Single vmcnt drain (one RT exposure).
__device__ __forceinline__ void stage64k(const char* src, char* dst, int tid){
  u32x4 r0,r1,r2,r3,r4,r5,r6,r7,r8,r9,ra,rb,rc,rd,re,rf;
  u64 a = (u64)(uintptr_t)src + (u64)tid*16;
  #define LD(reg, off) asm volatile("global_load_dwordx4 %0, %1, off sc0 sc1" \
                                    : "=v"(reg) : "v"(a + (off)) : "memory")
  LD(r0,0); LD(r1,4096); LD(r2,8192); LD(r3,12288);
  LD(r4,16384); LD(r5,20480); LD(r6,24576); LD(r7,28672);
  LD(r8,32768); LD(r9,36864); LD(ra,40960); LD(rb,45056);
  LD(rc,49152); LD(rd,53248); LD(re,57344); LD(rf,61440);
  #undef LD
  asm volatile("s_waitcnt vmcnt(0)" ::: "memory");
  u32x4* d = (u32x4*)(dst + tid*16);
  d[0]=r0; d[256]=r1; d[512]=r2; d[768]=r3;
  d[1024]=r4; d[1280]=r5; d[1536]=r6; d[1792]=r7;
  d[2048]=r8; d[2304]=r9; d[2560]=ra; d[2816]=rb;
  d[3072]=rc; d[3328]=rd; d[3584]=re; d[3840]=rf;
}

// Spin until all 128 u16 flags >= tgt. Wave-0 lanes 0..15 each poll 16B.
__device__ __forceinline__ void spin128(const unsigned short* f, unsigned tgt,
                                        int lane, u64 dl){
  if (lane < 16){
    u64 a = (u64)(uintptr_t)f + (u64)lane*16;
    while (true){
      u32x4 v;
      asm volatile("global_load_dwordx4 %0, %1, off sc0 sc1\n\ts_waitcnt vmcnt(0)"
                   : "=v"(v) : "v"(a) : "memory");
      bool ok = true;
      #pragma unroll
      for (int i=0;i<4;++i){
        unsigned u = v[i];
        ok = ok && ((u & 0xFFFFu) >= tgt) && ((u >> 16) >= tgt);
      }
      if (__all((int)ok)) break;
      if (rtick() > dl) break;
    }
  }
  asm volatile("" ::: "memory");
}

// ---------------- prep kernels ----------------

// x -> Xf: bf16(x+1) in MFMA-A fragment layout, 64KB per step  [r7-certified]
__global__ void prep_xfrag(const float* __restrict__ x, unsigned short* __restrict__ xf){
  int tid = blockIdx.x*256 + threadIdx.x;      // 2,097,152 total
  int k8 = tid & 127, row = (tid>>7)&31, t = tid>>12;
  const float* s = x + ((size_t)(t*32+row)*1024 + k8*8);
  f32x4 a = *reinterpret_cast<const f32x4*>(s);
  f32x4 b = *reinterpret_cast<const f32x4*>(s+4);
  f32x4 a1 = {a[0]+1.f,a[1]+1.f,a[2]+1.f,a[3]+1.f};
  f32x4 b1 = {b[0]+1.f,b[1]+1.f,b[2]+1.f,b[3]+1.f};
  bf16x8 v = packbf(a1,b1);
  *reinterpret_cast<bf16x8*>((char*)xf + (size_t)t*65536 + fragOff(row,k8)) = v;
}

// h0 -> HiniF (frag layout, both layers)  [r7-certified]
__global__ void prep_hfrag(const float* __restrict__ h0, unsigned short* __restrict__ hf){
  int tid = blockIdx.x*256 + threadIdx.x;      // 8192 total
  int k8 = tid & 127, row = (tid>>7)&31, L = tid>>12;
  const float* s = h0 + ((size_t)(L*32+row)*1024 + k8*8);
  f32x4 a = *reinterpret_cast<const f32x4*>(s);
  f32x4 b = *reinterpret_cast<const f32x4*>(s+4);
  bf16x8 v = packbf(a,b);
  *reinterpret_cast<bf16x8*>((char*)hf + (size_t)L*65536 + fragOff(row,k8)) = v;
}

__global__ void reduce_mean_f32(const float* __restrict__ src, float* __restrict__ out, float add){
  __shared__ float red[256];
  int t = blockIdx.x, tid = threadIdx.x;
  const float* p = src + (size_t)t*32768;
  float s = 0.f;
  for (int i = tid; i < 32768; i += 256) s += p[i];
  red[tid] = s; __syncthreads();
  for (int o = 128; o > 0; o >>= 1){ if (tid < o) red[tid] += red[tid+o]; __syncthreads(); }
  if (tid == 0) out[t] = red[0]*(1.f/32768.f) + add;
}

__global__ void prep_rs(const float* __restrict__ Wih0, const float* __restrict__ Whh0,
                        const float* __restrict__ Wih1, const float* __restrict__ Whh1,
                        const float* __restrict__ bih0, const float* __restrict__ bhh0,
                        const float* __restrict__ bih1, const float* __restrict__ bhh1,
                        float* __restrict__ rs, float* __restrict__ bias){
  int task = blockIdx.x*4 + (threadIdx.x >> 6);
  int lane = threadIdx.x & 63;
  int L = task >> 12, n = task & 4095;
  const float* pi = (L ? Wih1 : Wih0) + (size_t)n*1024;
  const float* ph = (L ? Whh1 : Whh0) + (size_t)n*1024;
  float s = 0.f;
  #pragma unroll
  for (int e = 0; e < 16; ++e){ int k = lane + e*64; s += pi[k] + ph[k]; }
  #pragma unroll
  for (int m = 32; m; m >>= 1) s += __shfl_xor(s, m);
  if (lane == 0){
    rs[task]   = s;
    bias[task] = (L ? bih1[n] : bih0[n]) + (L ? bhh1[n] : bhh0[n]);
  }
}

// ---------------- recurrent kernel ----------------
// grid 256 x 256. Blocks 0..127: layer 0; 128..255: layer 1 (1 step behind).
// Block bid owns h-cols jb=bid*8 (x4 gates = 32 ncols), same as r5.
// Wave w: rh=w>>1 (rows rh*16..+15), cg=w&1 (cols jb+cg*4..+3, x4 gates).
__global__ __launch_bounds__(256) void rec8(
    const unsigned short* __restrict__ Xf,     // [512][64KB] frag
    const unsigned short* __restrict__ HiniF,  // [2][64KB] frag
    unsigned short* __restrict__ Ring0,        // [512][32768] frag (y0)
    unsigned short* __restrict__ Ring1,        // [8][32768] frag (h1)
    float* __restrict__ out,
    const float* __restrict__ Wih0, const float* __restrict__ Whh0,
    const float* __restrict__ Wih1, const float* __restrict__ Whh1,
    const float* __restrict__ biasC, const float* __restrict__ rsC,  // [2*4096]
    const float* __restrict__ eps0, const float* __restrict__ c0,
    int* __restrict__ epsP,                    // [512][128]
    unsigned short* __restrict__ flag0,        // 128 u16 (256B)
    unsigned short* __restrict__ flag1)
{
  __shared__ char ldsW[65536];                 // first-half W slice, frag-linear
  __shared__ char ldsA[65536];                 // A-tile (h or y0)
  __shared__ float ldsPs[4];

  const int tid  = threadIdx.x;
  const int lane = tid & 63;
  const int w    = tid >> 6;
  const int L    = blockIdx.x >> 7;
  const int bid  = blockIdx.x & 127;
  const int rh   = w >> 1;
  const int cg   = w & 1;
  const int jb   = bid * 8;
  const int jc   = jb + cg*4;
  const int c    = lane & 15;
  const int q    = c >> 2;
  const int ncol = q*1024 + jc + (c & 3);
  const int koff = (lane >> 4) << 3;
  const u64 dl   = rtick() + DEADLINE_TICKS;

  // chain order per r5: L0 = x-then-h, L1 = h-then-y0.
  const float* Wfirst = L ? Whh1 : Wih0;       // -> LDS (first half of chain)
  const float* Wsec   = L ? Wih1 : Whh0;       // -> VGPR (second half)

  // ---- stage first-half W slice into LDS (fp32->bf16, frag-linear) ----
  for (int i = 0; i < 16; ++i){
    int fi = w*16 + i;                         // 0..63
    int cgx = fi >> 5, kt = fi & 31;
    int nn = q*1024 + jb + cgx*4 + (c & 3);
    const float* src = Wfirst + (size_t)nn*1024 + kt*32 + koff;
    f32x4 wa = *reinterpret_cast<const f32x4*>(src);
    f32x4 wb = *reinterpret_cast<const f32x4*>(src + 4);
    *reinterpret_cast<bf16x8*>(ldsW + fi*1024 + lane*16) = packbf(wa, wb);
  }
  // ---- second-half W into VGPRs ----
  bf16x8 wreg[32];
  {
    const float* src = Wsec + (size_t)ncol*1024 + koff;
    #pragma unroll
    for (int kt = 0; kt < 32; ++kt){
      f32x4 wa = *reinterpret_cast<const f32x4*>(src + kt*32);
      f32x4 wb = *reinterpret_cast<const f32x4*>(src + kt*32 + 4);
      wreg[kt] = packbf(wa, wb);
    }
  }
  __syncthreads();

  const float bia = biasC[L*4096 + ncol];
  const float rsv = rsC[L*4096 + ncol];
  const int jw = jc + (c & 3);
  float creg[4];
  #pragma unroll
  for (int r = 0; r < 4; ++r)
    creg[r] = c0[L*32768 + (rh*16 + (lane>>4)*4 + r)*1024 + jw];

  float* outHn = out + 16777216 + L*32768;
  float* outCn = out + 16777216 + 65536 + L*32768;
  const u64 myFlagA = (u64)(uintptr_t)((L ? flag1 : flag0) + bid);

  for (int t = 0; t < T_STEPS; ++t){
    f32x4 acc = {0.f, 0.f, 0.f, 0.f};
    float et;

    if (L == 0){
      // x-half FIRST (chain start, r5 order) — independent of h
      const char* Ax = (const char*)Xf + (size_t)t*65536;
      #pragma unroll 4
      for (int kt = 0; kt < 32; ++kt){
        bf16x8 a = ld_frag_plain(Ax + (kt*2 + rh)*1024 + lane*16);
        bf16x8 b = lds_frag(ldsW + (cg*32 + kt)*1024 + lane*16);
        acc = MFMA16(a, b, acc, 0, 0, 0);
      }
      et = eps0[t];
      if (w == 0 && t > 0) spin128(flag0, (unsigned)t, lane, dl);
      __syncthreads();
      const char* hsrc = (t == 0) ? (const char*)HiniF
                                  : (const char*)Ring0 + (size_t)(t-1)*65536;
      stage64k(hsrc, ldsA, tid);
      __syncthreads();
      // h-half continues the SAME accumulator chain
      #pragma unroll 4
      for (int kt = 0; kt < 32; ++kt){
        bf16x8 a = lds_frag(ldsA + (kt*2 + rh)*1024 + lane*16);
        acc = MFMA16(a, wreg[kt], acc, 0, 0, 0);
      }
    } else {
      // L1: h-half FIRST (r5 order)
      if (w == 0 && t > 0) spin128(flag1, (unsigned)t, lane, dl);
      __syncthreads();
      const char* hsrc = (t == 0) ? (const char*)HiniF + 65536
                                  : (const char*)Ring1 + (size_t)((t-1)&7)*65536;
      stage64k(hsrc, ldsA, tid);
      __syncthreads();
      #pragma unroll 4
      for (int kt = 0; kt < 32; ++kt){
        bf16x8 a = lds_frag(ldsA + (kt*2 + rh)*1024 + lane*16);
        bf16x8 b = lds_frag(ldsW + (cg*32 + kt)*1024 + lane*16);
        acc = MFMA16(a, b, acc, 0, 0, 0);
      }
      __syncthreads();                         // all waves done reading ldsA
      if (w == 0) spin128(flag0, (unsigned)(t+1), lane, dl);
      __syncthreads();
      // eps1[t] = exact fixed-point sum of 128 partials
      {
        const u64* ep = reinterpret_cast<const u64*>(epsP + (size_t)t*128);
        u64 v = AGLD(ep + lane);
        int s = (int)(unsigned)v + (int)(unsigned)(v >> 32);
        #pragma unroll
        for (int mm = 32; mm; mm >>= 1) s += __shfl_xor(s, mm);
        et = (float)s * 4.6566128730773926e-10f;   // / (2^16 * 32768)
      }
      stage64k((const char*)Ring0 + (size_t)t*65536, ldsA, tid);
      __syncthreads();
      // y0-half continues the chain
      #pragma unroll 4
      for (int kt = 0; kt < 32; ++kt){
        bf16x8 a = lds_frag(ldsA + (kt*2 + rh)*1024 + lane*16);
        acc = MFMA16(a, wreg[kt], acc, 0, 0, 0);
      }
    }

    // ---- epilogue (q-routing certified in r7 via y1) ----
    char* ringSlot = L ? ((char*)Ring1 + (size_t)(t & 7)*65536)
                       : ((char*)Ring0 + (size_t)t*65536);
    float hyv[4];
    float psum = 0.f;
    #pragma unroll
    for (int r = 0; r < 4; ++r){
      float g  = acc[r] + bia + et*rsv;
      float p4 = __shfl_xor(g, 4), p8 = __shfl_xor(g, 8), p12 = __shfl_xor(p4, 8);
      float iv = (q==0)?g:(q==1)?p4:(q==2)?p8:p12;
      float fv = (q==1)?g:(q==0)?p4:(q==3)?p8:p12;
      float gv = (q==2)?g:(q==3)?p4:(q==0)?p8:p12;
      float ov = (q==3)?g:(q==2)?p4:(q==1)?p8:p12;
      iv = fminf(fmaxf(0.2f*iv + 0.5f, 0.f), 1.f);
      fv = fminf(fmaxf(0.2f*fv + 0.5f, 0.f), 1.f);
      gv = fminf(fmaxf(gv, -1.f), 1.f);
      ov = fminf(fmaxf(0.2f*ov + 0.5f, 0.f), 1.f);
      float cc = fv*(creg[r] + et) + iv*gv;
      creg[r] = cc;
      float hy = ov * fminf(fmaxf(cc, -1.f), 1.f);
      hyv[r] = hy;
      if (c < 4) psum += hy;

      unsigned short hu = f2bf(hy);
      unsigned p2 = (unsigned)hu | (((unsigned)__shfl_xor((int)hu, 1)) << 16);
      unsigned q2 = (unsigned)__shfl_xor((int)p2, 2);
      if (c == 0){
        int sub = (lane>>4)*4 + r;
        size_t bo = (size_t)((jb>>5)*2 + rh)*1024
                  + (size_t)(sub | (((jb>>3)&3)<<4))*16 + (size_t)cg*8;
        AGST(reinterpret_cast<u64*>(ringSlot + bo), (u64)p2 | ((u64)q2 << 32));
      }
    }
    if (L == 0){
      #pragma unroll
      for (int mm = 32; mm; mm >>= 1) psum += __shfl_xor(psum, mm);
      if (lane == 0) ldsPs[w] = psum;
    }
    asm volatile("s_waitcnt vmcnt(0)" ::: "memory");   // drain ring publishes
    __syncthreads();
    if (tid == 0){
      if (L == 0){
        float bs = ldsPs[0] + ldsPs[1] + ldsPs[2] + ldsPs[3];
        AGST(reinterpret_cast<unsigned*>(epsP + (size_t)t*128 + bid),
             (unsigned)(int)llrintf(bs*65536.f));
        asm volatile("s_waitcnt vmcnt(0)" ::: "memory");
      }
      asm volatile("global_store_short %0, %1, off sc0 sc1"
                   :: "v"(myFlagA), "v"((unsigned)(t+1)) : "memory");
    }

    // ---- off-critical-path outputs ----
    if (L){
      #pragma unroll
      for (int r = 0; r < 4; ++r){
        float hy = hyv[r];
        float f1 = __shfl_xor(hy, 1), f2 = __shfl_xor(hy, 2), f3 = __shfl_xor(f1, 2);
        if (c == 0){
          int row = rh*16 + (lane>>4)*4 + r;
          f32x4 o4 = {hy, f1, f2, f3};
          *reinterpret_cast<f32x4*>(out + (size_t)t*32768 + row*1024 + jc) = o4;
        }
      }
    }
    if (t == T_STEPS-1){
      #pragma unroll
      for (int r = 0; r < 4; ++r)
        if (c < 4){
          int row = rh*16 + (lane>>4)*4 + r;
          outHn[row*1024 + jw] = hyv[r];
          outCn[row*1024 + jw] = creg[r];
        }
    }
  }
}

// ---------------- host ----------------

extern "C" void kernel_launch(void* const* d_in, const int* in_sizes, int n_in,
                              void* d_out, int out_size, void* d_ws, size_t ws_size,
                              hipStream_t stream)
{
  const float* x    = (const float*)d_in[0];
  const float* h0   = (const float*)d_in[1];
  const float* c0   = (const float*)d_in[2];
  const float* Wih0 = (const float*)d_in[3];
  const float* Whh0 = (const float*)d_in[4];
  const float* bih0 = (const float*)d_in[5];
  const float* bhh0 = (const float*)d_in[6];
  const float* Wih1 = (const float*)d_in[7];
  const float* Whh1 = (const float*)d_in[8];
  const float* bih1 = (const float*)d_in[9];
  const float* bhh1 = (const float*)d_in[10];
  float* out = (float*)d_out;

  char* ws = (char*)d_ws;
  size_t off = 0;
  auto alloc = [&](size_t bytes)->char* {
    char* p = ws + off; off += (bytes + 255) & ~(size_t)255; return p;
  };
  unsigned short* Xf    = (unsigned short*)alloc((size_t)T_STEPS*65536);   // 32MB
  unsigned short* Ring0 = (unsigned short*)alloc((size_t)T_STEPS*65536);   // 32MB
  unsigned short* Ring1 = (unsigned short*)alloc((size_t)8*65536);         // 512KB
  unsigned short* HiniF = (unsigned short*)alloc(2*65536);
  float* eps0 = (float*)alloc(T_STEPS*4);
  float* bias = (float*)alloc(2*4096*4);
  float* rs   = (float*)alloc(2*4096*4);
  int*   epsP = (int*)alloc((size_t)T_STEPS*128*4);                        // 256KB
  // per-launch-zeroed flags: 2 x 128 u16 (flags only touched via sc1 ops,
  // so no dirty-L2 resurrection across graph replays)
  char* sync = alloc(1024);
  unsigned short* flag0 = (unsigned short*)sync;
  unsigned short* flag1 = (unsigned short*)(sync + 512);
  if (off > ws_size)
    fprintf(stderr, "HardLSTM: ws too small, need %zu have %zu\n", off, ws_size);

  hipMemsetAsync(sync, 0, 1024, stream);
  prep_xfrag<<<8192, 256, 0, stream>>>(x, Xf);
  prep_hfrag<<<32, 256, 0, stream>>>(h0, HiniF);
  reduce_mean_f32<<<T_STEPS, 256, 0, stream>>>(x, eps0, 1.0f);  // mean(x_t)+1
  prep_rs<<<2048, 256, 0, stream>>>(Wih0, Whh0, Wih1, Whh1,
                                    bih0, bhh0, bih1, bhh1, rs, bias);

  rec8<<<256, 256, 0, stream>>>(Xf, HiniF, Ring0, Ring1, out,
      Wih0, Whh0, Wih1, Whh1, bias, rs, eps0, c0, epsP, flag0, flag1);
}